// Round 9
// baseline (56.072 us; speedup 1.0000x reference)
//
#include <hip/hip_runtime.h>
#include <math.h>

// TensoIR physical rendering: N points x L lights -> 4 (N,3) outputs
// (rgb, wo_indir, wo_vis, indir), each linear->sRGB'd after the light sum.
//
// R9 changes vs R4 (best 52.7us; VALU-issue-bound: VALUBusy ~60%, memory
// floors ~21us HBM / ~11us L2 both far below):
//  - PACKED FP32: process lights in pairs per lane; the entire per-pair
//    pipeline (dots, clamps, Schlick, GGX denom, 3 color channels, 9
//    accumulators) written as float2 ext-vector ops so LLVM emits
//    v_pk_fma_f32 / v_pk_mul_f32 / v_pk_min/max_f32 (full-rate 2xf32 on
//    CDNA2+). Only rsq/exp/rcp (trans pipe) and mask-selects stay scalar.
//  - structure, staging, lane->light mapping, algebra = R4 exactly.

#define PI_F     3.14159265358979323846f
#define FOURPI_F (4.0f * PI_F)
#define MAXL     512

typedef __attribute__((ext_vector_type(2))) float pf2;

__device__ __forceinline__ float fast_rcp(float x)  { float r; asm("v_rcp_f32 %0, %1" : "=v"(r) : "v"(x)); return r; }
__device__ __forceinline__ float fast_rsq(float x)  { float r; asm("v_rsq_f32 %0, %1" : "=v"(r) : "v"(x)); return r; }
__device__ __forceinline__ float fast_exp2(float x) { float r; asm("v_exp_f32 %0, %1" : "=v"(r) : "v"(x)); return r; }
__device__ __forceinline__ float fast_log2(float x) { float r; asm("v_log_f32 %0, %1" : "=v"(r) : "v"(x)); return r; }

__device__ __forceinline__ pf2 pk2(float a, float b) { pf2 r; r.x = a; r.y = b; return r; }
__device__ __forceinline__ pf2 pbc(float a)          { pf2 r; r.x = a; r.y = a; return r; }
__device__ __forceinline__ pf2 pfma(pf2 a, pf2 b, pf2 c) { return __builtin_elementwise_fma(a, b, c); }
__device__ __forceinline__ pf2 pmin(pf2 a, pf2 b)        { return __builtin_elementwise_min(a, b); }
__device__ __forceinline__ pf2 pmax(pf2 a, pf2 b)        { return __builtin_elementwise_max(a, b); }
__device__ __forceinline__ pf2 prsq(pf2 x) { pf2 r; r.x = fast_rsq(x.x); r.y = fast_rsq(x.y); return r; }
__device__ __forceinline__ pf2 prcp(pf2 x) { pf2 r; r.x = fast_rcp(x.x); r.y = fast_rcp(x.y); return r; }
__device__ __forceinline__ pf2 pexp2(pf2 x){ pf2 r; r.x = fast_exp2(x.x); r.y = fast_exp2(x.y); return r; }

__device__ __forceinline__ float lin2srgb(float x) {
  float lin = 12.92f * x;
  float xe  = fmaxf(x, 1e-8f);
  float e   = 1.055f * fast_exp2(fast_log2(xe) * (1.0f / 2.4f)) - 0.055f;
  return (x <= 0.0031308f) ? lin : e;
}

__device__ __forceinline__ float clamp01(float x) { return fminf(fmaxf(x, 0.0f), 1.0f); }
__device__ __forceinline__ float clampe(float x)  { return fminf(fmaxf(x, 1e-6f), 1.0f); }

// LC = compile-time light count (0 => runtime L)
template <int LC>
__global__ void __launch_bounds__(256, 4)
tensoir_render(const float* __restrict__ viewdirs,  // (N,3)
               const float* __restrict__ albedo,    // (N,3)
               const float* __restrict__ roughness, // (N,1)
               const float* __restrict__ fresnel,   // (N,3)
               const float* __restrict__ normal,    // (N,3)
               const float* __restrict__ light_dirs,// (L,3)
               const float* __restrict__ law,       // (L,)
               const float* __restrict__ env_rgbs,  // (L,3)
               const float* __restrict__ visibility,// (N,L,1)
               const float* __restrict__ indirect,  // (N,L,3)
               float* __restrict__ out,             // 4*N*3
               int N, int Lrt) {
  __shared__ float4 s_ld[MAXL];   // normalized light dir xyz, area weight
  __shared__ float4 s_env[MAXL];  // env rgb, pad

  const int L = LC ? LC : Lrt;
  const int tid = threadIdx.x;
  const int lane = tid & 63;
  int n = blockIdx.x * 4 + (tid >> 6);
  if (n >= N) n = N - 1;  // tail: duplicate work, identical writes

  // per-point scalar loads issued before staging (independent)
  float vx = -viewdirs[3 * n + 0], vy = -viewdirs[3 * n + 1], vz = -viewdirs[3 * n + 2];
  float nx = normal[3 * n + 0], ny = normal[3 * n + 1], nz = normal[3 * n + 2];
  float rough0 = roughness[n];
  const float fr = fresnel[3 * n + 0], fg = fresnel[3 * n + 1], fb = fresnel[3 * n + 2];
  float ar0 = albedo[3 * n + 0], ag0 = albedo[3 * n + 1], ab0 = albedo[3 * n + 2];

  // stage light table (per block)
  for (int l = tid; l < L && l < MAXL; l += 256) {
    float lx = light_dirs[3 * l + 0];
    float ly = light_dirs[3 * l + 1];
    float lz = light_dirs[3 * l + 2];
    float inv = fast_rsq(fmaxf(lx * lx + ly * ly + lz * lz, 1e-12f));
    s_ld[l]  = make_float4(lx * inv, ly * inv, lz * inv, law[l]);
    s_env[l] = make_float4(env_rgbs[3 * l + 0], env_rgbs[3 * l + 1],
                           env_rgbs[3 * l + 2], 0.0f);
  }
  __syncthreads();

  // ---- per-point (wave-uniform) setup ----
  {
    float inv = fast_rsq(fmaxf(vx * vx + vy * vy + vz * vz, 1e-12f));
    vx *= inv; vy *= inv; vz *= inv;
  }
  {
    float inv = fast_rsq(fmaxf(nx * nx + ny * ny + nz * nz, 1e-12f));
    nx *= inv; ny *= inv; nz *= inv;
  }
  const float rough  = clamp01(rough0 * 0.9f + 0.09f);
  const float alpha  = rough * rough;
  const float alpha2 = alpha * alpha;
  const float a2m1   = alpha2 - 1.0f;
  const float kk     = (alpha + 2.0f * rough + 1.0f) * 0.125f;
  const float onemk  = 1.0f - kk;

  const float ar = clamp01(ar0) * (1.0f / PI_F);
  const float ag = clamp01(ag0) * (1.0f / PI_F);
  const float ab = clamp01(ab0) * (1.0f / PI_F);

  const float NoV0 = vx * nx + vy * ny + vz * nz;
  const float sgn  = (NoV0 >= 0.0f) ? 1.0f : -1.0f;
  const float aNoV = fabsf(NoV0);              // Nf . V (exact)
  const float NoV  = clampe(aNoV);
  const float nom1 = NoV * onemk + kk;
  const float c1   = FOURPI_F * nom1;          // hoisted constant factor

  const float* visrow = visibility + (size_t)n * L;
  const float* indrow = indirect + (size_t)n * L * 3;

  if (LC) {
    // ---- packed-f32 path: lights in pairs per lane ----
    const pf2 nx2 = pbc(nx), ny2 = pbc(ny), nz2 = pbc(nz);
    const pf2 vx2 = pbc(vx), vy2 = pbc(vy), vz2 = pbc(vz);
    const pf2 sgn2 = pbc(sgn), aNoV2 = pbc(aNoV);
    const pf2 a2m1_2 = pbc(a2m1), onemk2 = pbc(onemk), kk2 = pbc(kk);
    const pf2 c1_2 = pbc(c1), alpha2_2 = pbc(alpha2);
    const pf2 fr2 = pbc(fr), fg2 = pbc(fg), fb2 = pbc(fb);
    const pf2 omfr2 = pbc(1.0f - fr), omfg2 = pbc(1.0f - fg), omfb2 = pbc(1.0f - fb);
    const pf2 ar2 = pbc(ar), ag2 = pbc(ag), ab2 = pbc(ab);
    const pf2 zero2 = pbc(0.0f), one2 = pbc(1.0f), eps2 = pbc(1e-6f);
    const pf2 two2 = pbc(2.0f), tiny2 = pbc(1e-12f), fourpi2 = pbc(FOURPI_F);
    const pf2 cf1 = pbc(-5.55473f), cf2 = pbc(-6.98316f);

    pf2 s1r = zero2, s1g = zero2, s1b = zero2;
    pf2 s2r = zero2, s2g = zero2, s2b = zero2;
    pf2 s3r = zero2, s3g = zero2, s3b = zero2;

    constexpr int NPAIR = LC ? LC / 128 : 1;   // 4 bundles of 2 lights
#pragma unroll
    for (int j = 0; j < NPAIR; ++j) {
      const int i0 = lane + 128 * j;
      const int i1 = i0 + 64;

      const float4 ldA = s_ld[i0], ldB = s_ld[i1];
      const float4 evA = s_env[i0], evB = s_env[i1];
      const float  vA  = visrow[i0], vB = visrow[i1];
      const float  irA = indrow[3 * i0 + 0], igA = indrow[3 * i0 + 1], ibA = indrow[3 * i0 + 2];
      const float  irB = indrow[3 * i1 + 0], igB = indrow[3 * i1 + 1], ibB = indrow[3 * i1 + 2];

      const pf2 lx = pk2(ldA.x, ldB.x), ly = pk2(ldA.y, ldB.y), lz = pk2(ldA.z, ldB.z);
      const pf2 lw = pk2(ldA.w, ldB.w);

      const pf2 cos0 = pfma(lz, nz2, pfma(ly, ny2, lx * nx2));   // L . N
      const pf2 LoV  = pfma(lz, vz2, pfma(ly, vy2, lx * vx2));   // L . V

      const pf2 cosine = pmax(cos0, zero2);
      const pf2 w      = cosine * lw;

      const pf2 NoL0 = sgn2 * cos0;
      const pf2 NoL  = pmin(pmax(NoL0, eps2), one2);

      const pf2 h2   = pfma(two2, LoV, two2);
      const pf2 hinv = prsq(pmax(h2, tiny2));
      const pf2 VoH  = pmin(pmax((one2 + LoV) * hinv, eps2), one2);
      const pf2 NoH  = pmin(pmax((NoL0 + aNoV2) * hinv, eps2), one2);

      const pf2 FMi = pfma(cf1, VoH, cf2) * VoH;
      const pf2 pw2 = pexp2(FMi);
      const pf2 nom0 = pfma(NoH * NoH, a2m1_2, one2);
      const pf2 nom2 = pfma(NoL, onemk2, kk2);
      const pf2 nom  = pmin(pmax(c1_2 * (nom0 * nom0) * nom2, eps2), fourpi2);
      const pf2 ss   = alpha2_2 * prcp(nom);

      const pf2 br = pfma(pfma(omfr2, pw2, fr2), ss, ar2);
      const pf2 bg = pfma(pfma(omfg2, pw2, fg2), ss, ag2);
      const pf2 bb = pfma(pfma(omfb2, pw2, fb2), ss, ab2);

      const bool mA = cos0.x > 1e-6f, mB = cos0.y > 1e-6f;
      const pf2 vism = pk2(mA ? vA : 0.0f, mB ? vB : 0.0f);
      const pf2 irm  = pk2(mA ? irA : 0.0f, mB ? irB : 0.0f);
      const pf2 igm  = pk2(mA ? igA : 0.0f, mB ? igB : 0.0f);
      const pf2 ibm  = pk2(mA ? ibA : 0.0f, mB ? ibB : 0.0f);

      const pf2 evr = pk2(evA.x, evB.x), evg = pk2(evA.y, evB.y), evb = pk2(evA.z, evB.z);
      const pf2 twr = br * w, twg = bg * w, twb = bb * w;

      s1r = pfma(twr, vism * evr, s1r);
      s1g = pfma(twg, vism * evg, s1g);
      s1b = pfma(twb, vism * evb, s1b);
      s2r = pfma(twr, evr, s2r);
      s2g = pfma(twg, evg, s2g);
      s2b = pfma(twb, evb, s2b);
      s3r = pfma(twr, irm, s3r);
      s3g = pfma(twg, igm, s3g);
      s3b = pfma(twb, ibm, s3b);
    }

    // collapse packed halves, then wave-reduce
    float t1r = s1r.x + s1r.y, t1g = s1g.x + s1g.y, t1b = s1b.x + s1b.y;
    float t2r = s2r.x + s2r.y, t2g = s2g.x + s2g.y, t2b = s2b.x + s2b.y;
    float t3r = s3r.x + s3r.y, t3g = s3g.x + s3g.y, t3b = s3b.x + s3b.y;

#define WAVE_RED(v)                 \
    do {                            \
      v += __shfl_xor(v, 32);       \
      v += __shfl_xor(v, 16);       \
      v += __shfl_xor(v, 8);        \
      v += __shfl_xor(v, 4);        \
      v += __shfl_xor(v, 2);        \
      v += __shfl_xor(v, 1);        \
    } while (0)
    WAVE_RED(t1r); WAVE_RED(t1g); WAVE_RED(t1b);
    WAVE_RED(t2r); WAVE_RED(t2g); WAVE_RED(t2b);
    WAVE_RED(t3r); WAVE_RED(t3g); WAVE_RED(t3b);
#undef WAVE_RED

    if (lane == 0) {
      const size_t stride = (size_t)3 * N;
      float* o0 = out + 3 * (size_t)n;             // rgb
      float* o1 = o0 + stride;                     // wo_indir
      float* o2 = o1 + stride;                     // wo_vis
      float* o3 = o2 + stride;                     // indir
      o0[0] = lin2srgb(clamp01(t1r + t3r));
      o0[1] = lin2srgb(clamp01(t1g + t3g));
      o0[2] = lin2srgb(clamp01(t1b + t3b));
      o1[0] = lin2srgb(t1r); o1[1] = lin2srgb(t1g); o1[2] = lin2srgb(t1b);
      o2[0] = lin2srgb(t2r); o2[1] = lin2srgb(t2g); o2[2] = lin2srgb(t2b);
      o3[0] = lin2srgb(t3r); o3[1] = lin2srgb(t3g); o3[2] = lin2srgb(t3b);
    }
  } else {
    // ---- scalar fallback (runtime L) ----
    float s1r = 0, s1g = 0, s1b = 0;
    float s2r = 0, s2g = 0, s2b = 0;
    float s3r = 0, s3g = 0, s3b = 0;
    const float omfr = 1.0f - fr, omfg = 1.0f - fg, omfb = 1.0f - fb;

    for (int i = lane; i < L; i += 64) {
      const float4 ld = s_ld[i];
      const float4 ev = s_env[i];
      const float visv = visrow[i];
      const float ir = indrow[3 * i + 0];
      const float ig = indrow[3 * i + 1];
      const float ib = indrow[3 * i + 2];

      const float cos0 = ld.x * nx + ld.y * ny + ld.z * nz;
      const float LoV  = ld.x * vx + ld.y * vy + ld.z * vz;
      const float cosine = fmaxf(cos0, 0.0f);
      const bool  mask   = cos0 > 1e-6f;
      const float w      = cosine * ld.w;
      const float NoL0 = sgn * cos0;
      const float NoL  = clampe(NoL0);
      const float h2   = fmaf(2.0f, LoV, 2.0f);
      const float hinv = fast_rsq(fmaxf(h2, 1e-12f));
      const float VoH  = clampe((1.0f + LoV) * hinv);
      const float NoH  = clampe((NoL0 + aNoV) * hinv);
      const float FMi = (-5.55473f * VoH - 6.98316f) * VoH;
      const float p2  = fast_exp2(FMi);
      const float nom0 = fmaf(NoH * NoH, a2m1, 1.0f);
      const float nom2 = fmaf(NoL, onemk, kk);
      const float nom  = fminf(fmaxf(c1 * (nom0 * nom0) * nom2, 1e-6f), FOURPI_F);
      const float ss   = alpha2 * fast_rcp(nom);
      const float br = fmaf(fmaf(omfr, p2, fr), ss, ar);
      const float bg = fmaf(fmaf(omfg, p2, fg), ss, ag);
      const float bb = fmaf(fmaf(omfb, p2, fb), ss, ab);
      const float vism = mask ? visv : 0.0f;
      const float irm  = mask ? ir : 0.0f;
      const float igm  = mask ? ig : 0.0f;
      const float ibm  = mask ? ib : 0.0f;
      const float twr = br * w, twg = bg * w, twb = bb * w;
      s1r = fmaf(twr, vism * ev.x, s1r);
      s1g = fmaf(twg, vism * ev.y, s1g);
      s1b = fmaf(twb, vism * ev.z, s1b);
      s2r = fmaf(twr, ev.x, s2r);
      s2g = fmaf(twg, ev.y, s2g);
      s2b = fmaf(twb, ev.z, s2b);
      s3r = fmaf(twr, irm, s3r);
      s3g = fmaf(twg, igm, s3g);
      s3b = fmaf(twb, ibm, s3b);
    }

#define WAVE_RED(v)                 \
    do {                            \
      v += __shfl_xor(v, 32);       \
      v += __shfl_xor(v, 16);       \
      v += __shfl_xor(v, 8);        \
      v += __shfl_xor(v, 4);        \
      v += __shfl_xor(v, 2);        \
      v += __shfl_xor(v, 1);        \
    } while (0)
    WAVE_RED(s1r); WAVE_RED(s1g); WAVE_RED(s1b);
    WAVE_RED(s2r); WAVE_RED(s2g); WAVE_RED(s2b);
    WAVE_RED(s3r); WAVE_RED(s3g); WAVE_RED(s3b);
#undef WAVE_RED

    if (lane == 0) {
      const size_t stride = (size_t)3 * N;
      float* o0 = out + 3 * (size_t)n;
      float* o1 = o0 + stride;
      float* o2 = o1 + stride;
      float* o3 = o2 + stride;
      o0[0] = lin2srgb(clamp01(s1r + s3r));
      o0[1] = lin2srgb(clamp01(s1g + s3g));
      o0[2] = lin2srgb(clamp01(s1b + s3b));
      o1[0] = lin2srgb(s1r); o1[1] = lin2srgb(s1g); o1[2] = lin2srgb(s1b);
      o2[0] = lin2srgb(s2r); o2[1] = lin2srgb(s2g); o2[2] = lin2srgb(s2b);
      o3[0] = lin2srgb(s3r); o3[1] = lin2srgb(s3g); o3[2] = lin2srgb(s3b);
    }
  }
}

extern "C" void kernel_launch(void* const* d_in, const int* in_sizes, int n_in,
                              void* d_out, int out_size, void* d_ws, size_t ws_size,
                              hipStream_t stream) {
  const float* viewdirs   = (const float*)d_in[0];
  const float* albedo     = (const float*)d_in[1];
  const float* roughness  = (const float*)d_in[2];
  const float* fresnel    = (const float*)d_in[3];
  const float* normal     = (const float*)d_in[4];
  const float* light_dirs = (const float*)d_in[5];
  const float* law        = (const float*)d_in[6];
  const float* env_rgbs   = (const float*)d_in[7];
  const float* visibility = (const float*)d_in[8];
  const float* indirect   = (const float*)d_in[9];
  float* out = (float*)d_out;

  const int N = in_sizes[0] / 3;
  const int L = in_sizes[6];   // light_area_weight is (L,)

  dim3 block(256);
  dim3 grid((N + 3) / 4);  // 4 points (waves) per block

  if (L == 512) {
    hipLaunchKernelGGL(tensoir_render<512>, grid, block, 0, stream,
                       viewdirs, albedo, roughness, fresnel, normal,
                       light_dirs, law, env_rgbs, visibility, indirect,
                       out, N, L);
  } else {
    hipLaunchKernelGGL(tensoir_render<0>, grid, block, 0, stream,
                       viewdirs, albedo, roughness, fresnel, normal,
                       light_dirs, law, env_rgbs, visibility, indirect,
                       out, N, L);
  }
}

// Round 10
// 52.492 us; speedup vs baseline: 1.0682x; 1.0682x over previous
//
#include <hip/hip_runtime.h>
#include <math.h>

// TensoIR physical rendering: N points x L lights -> 4 (N,3) outputs
// (rgb, wo_indir, wo_vis, indir), each linear->sRGB'd after the light sum.
//
// R10 = R4 exactly (best: 52.7us) + XCD-aware block swizzle.
// Null ledger: R3 consecutive-light float4 (-12%), R5 no-LDS (-16%),
// R6 explicit load hoist (0), R8 fat-block staging amortization (0),
// R9 packed-f32 math (-6%). => CU-side levers exhausted; residual is
// memory-system feed efficiency. Swizzle gives each XCD a contiguous
// 1/8th of the point range (32MB window) instead of round-robin over
// the full 256MB -> better DRAM/L3 locality per XCD.

#define PI_F     3.14159265358979323846f
#define FOURPI_F (4.0f * PI_F)
#define MAXL     512

__device__ __forceinline__ float fast_rcp(float x)  { float r; asm("v_rcp_f32 %0, %1" : "=v"(r) : "v"(x)); return r; }
__device__ __forceinline__ float fast_rsq(float x)  { float r; asm("v_rsq_f32 %0, %1" : "=v"(r) : "v"(x)); return r; }
__device__ __forceinline__ float fast_exp2(float x) { float r; asm("v_exp_f32 %0, %1" : "=v"(r) : "v"(x)); return r; }
__device__ __forceinline__ float fast_log2(float x) { float r; asm("v_log_f32 %0, %1" : "=v"(r) : "v"(x)); return r; }

__device__ __forceinline__ float lin2srgb(float x) {
  float lin = 12.92f * x;
  float xe  = fmaxf(x, 1e-8f);
  float e   = 1.055f * fast_exp2(fast_log2(xe) * (1.0f / 2.4f)) - 0.055f;
  return (x <= 0.0031308f) ? lin : e;
}

__device__ __forceinline__ float clamp01(float x) { return fminf(fmaxf(x, 0.0f), 1.0f); }
__device__ __forceinline__ float clampe(float x)  { return fminf(fmaxf(x, 1e-6f), 1.0f); }

// LC = compile-time light count (0 => runtime L)
template <int LC>
__global__ void __launch_bounds__(256)
tensoir_render(const float* __restrict__ viewdirs,  // (N,3)
               const float* __restrict__ albedo,    // (N,3)
               const float* __restrict__ roughness, // (N,1)
               const float* __restrict__ fresnel,   // (N,3)
               const float* __restrict__ normal,    // (N,3)
               const float* __restrict__ light_dirs,// (L,3)
               const float* __restrict__ law,       // (L,)
               const float* __restrict__ env_rgbs,  // (L,3)
               const float* __restrict__ visibility,// (N,L,1)
               const float* __restrict__ indirect,  // (N,L,3)
               float* __restrict__ out,             // 4*N*3
               int N, int Lrt) {
  __shared__ float4 s_ld[MAXL];   // normalized light dir xyz, area weight
  __shared__ float4 s_env[MAXL];  // env rgb, pad

  const int L = LC ? LC : Lrt;
  const int tid = threadIdx.x;
  const int lane = tid & 63;

  // XCD-aware swizzle: each of the 8 XCDs gets a contiguous 1/8th of the
  // block range (bijective since nwg % 8 == 0; identity otherwise).
  int bid = blockIdx.x;
  const int nwg = gridDim.x;
  if ((nwg & 7) == 0) {
    const int q = nwg >> 3;
    bid = (bid & 7) * q + (bid >> 3);
  }

  int n = bid * 4 + (tid >> 6);
  if (n >= N) n = N - 1;  // tail: duplicate work, identical writes

  // per-point scalar loads issued before staging (independent)
  float vx = -viewdirs[3 * n + 0], vy = -viewdirs[3 * n + 1], vz = -viewdirs[3 * n + 2];
  float nx = normal[3 * n + 0], ny = normal[3 * n + 1], nz = normal[3 * n + 2];
  float rough0 = roughness[n];
  const float fr = fresnel[3 * n + 0], fg = fresnel[3 * n + 1], fb = fresnel[3 * n + 2];
  float ar0 = albedo[3 * n + 0], ag0 = albedo[3 * n + 1], ab0 = albedo[3 * n + 2];

  // stage light table (per block)
  for (int l = tid; l < L && l < MAXL; l += 256) {
    float lx = light_dirs[3 * l + 0];
    float ly = light_dirs[3 * l + 1];
    float lz = light_dirs[3 * l + 2];
    float inv = fast_rsq(fmaxf(lx * lx + ly * ly + lz * lz, 1e-12f));
    s_ld[l]  = make_float4(lx * inv, ly * inv, lz * inv, law[l]);
    s_env[l] = make_float4(env_rgbs[3 * l + 0], env_rgbs[3 * l + 1],
                           env_rgbs[3 * l + 2], 0.0f);
  }
  __syncthreads();

  // ---- per-point (wave-uniform) setup ----
  {
    float inv = fast_rsq(fmaxf(vx * vx + vy * vy + vz * vz, 1e-12f));
    vx *= inv; vy *= inv; vz *= inv;
  }
  {
    float inv = fast_rsq(fmaxf(nx * nx + ny * ny + nz * nz, 1e-12f));
    nx *= inv; ny *= inv; nz *= inv;
  }
  const float rough  = clamp01(rough0 * 0.9f + 0.09f);
  const float alpha  = rough * rough;
  const float alpha2 = alpha * alpha;
  const float a2m1   = alpha2 - 1.0f;
  const float kk     = (alpha + 2.0f * rough + 1.0f) * 0.125f;
  const float onemk  = 1.0f - kk;

  const float omfr = 1.0f - fr, omfg = 1.0f - fg, omfb = 1.0f - fb;
  const float ar = clamp01(ar0) * (1.0f / PI_F);
  const float ag = clamp01(ag0) * (1.0f / PI_F);
  const float ab = clamp01(ab0) * (1.0f / PI_F);

  const float NoV0 = vx * nx + vy * ny + vz * nz;
  const float sgn  = (NoV0 >= 0.0f) ? 1.0f : -1.0f;
  const float aNoV = fabsf(NoV0);              // Nf . V (exact)
  const float NoV  = clampe(aNoV);
  const float nom1 = NoV * onemk + kk;
  const float c1   = FOURPI_F * nom1;          // hoisted constant factor

  // 9 accumulators: {wo_indir, wo_vis, indir} x {r,g,b}; rgb = wo_indir+indir.
  float s1r = 0, s1g = 0, s1b = 0;
  float s2r = 0, s2g = 0, s2b = 0;
  float s3r = 0, s3g = 0, s3b = 0;

  const float* visrow = visibility + (size_t)n * L;
  const float* indrow = indirect + (size_t)n * L * 3;

  auto body = [&](int i) {
    const float4 ld = s_ld[i];
    const float4 ev = s_env[i];
    const float visv = visrow[i];
    const float ir = indrow[3 * i + 0];
    const float ig = indrow[3 * i + 1];
    const float ib = indrow[3 * i + 2];

    // two dot products only (|L|=|V|=|N|=1 identities)
    const float cos0 = ld.x * nx + ld.y * ny + ld.z * nz;   // L . N
    const float LoV  = ld.x * vx + ld.y * vy + ld.z * vz;   // L . V

    const float cosine = fmaxf(cos0, 0.0f);
    const bool  mask   = cos0 > 1e-6f;
    const float w      = cosine * ld.w;

    const float NoL0 = sgn * cos0;                           // Nf . L
    const float NoL  = clampe(NoL0);

    const float h2   = fmaf(2.0f, LoV, 2.0f);                // |L+V|^2
    const float hinv = fast_rsq(fmaxf(h2, 1e-12f));
    const float VoH  = clampe((1.0f + LoV) * hinv);          // V.(L+V)/|h|
    const float NoH  = clampe((NoL0 + aNoV) * hinv);         // Nf.(L+V)/|h|

    const float FMi = (-5.55473f * VoH - 6.98316f) * VoH;
    const float p2  = fast_exp2(FMi);
    const float nom0 = fmaf(NoH * NoH, a2m1, 1.0f);
    const float nom2 = fmaf(NoL, onemk, kk);
    const float nom  = fminf(fmaxf(c1 * (nom0 * nom0) * nom2, 1e-6f), FOURPI_F);
    const float ss   = alpha2 * fast_rcp(nom);

    const float br = fmaf(fmaf(omfr, p2, fr), ss, ar);
    const float bg = fmaf(fmaf(omfg, p2, fg), ss, ag);
    const float bb = fmaf(fmaf(omfb, p2, fb), ss, ab);

    const float vism = mask ? visv : 0.0f;
    const float irm  = mask ? ir : 0.0f;
    const float igm  = mask ? ig : 0.0f;
    const float ibm  = mask ? ib : 0.0f;

    const float twr = br * w, twg = bg * w, twb = bb * w;

    s1r = fmaf(twr, vism * ev.x, s1r);
    s1g = fmaf(twg, vism * ev.y, s1g);
    s1b = fmaf(twb, vism * ev.z, s1b);
    s2r = fmaf(twr, ev.x, s2r);
    s2g = fmaf(twg, ev.y, s2g);
    s2b = fmaf(twb, ev.z, s2b);
    s3r = fmaf(twr, irm, s3r);
    s3g = fmaf(twg, igm, s3g);
    s3b = fmaf(twb, ibm, s3b);
  };

  if (LC) {
    constexpr int NITER = LC ? LC / 64 : 1;
#pragma unroll
    for (int j = 0; j < NITER; ++j) body(lane + 64 * j);
  } else {
    for (int i = lane; i < L; i += 64) body(i);
  }

#define WAVE_RED(v)                 \
  do {                              \
    v += __shfl_xor(v, 32);         \
    v += __shfl_xor(v, 16);         \
    v += __shfl_xor(v, 8);          \
    v += __shfl_xor(v, 4);          \
    v += __shfl_xor(v, 2);          \
    v += __shfl_xor(v, 1);          \
  } while (0)
  WAVE_RED(s1r); WAVE_RED(s1g); WAVE_RED(s1b);
  WAVE_RED(s2r); WAVE_RED(s2g); WAVE_RED(s2b);
  WAVE_RED(s3r); WAVE_RED(s3g); WAVE_RED(s3b);
#undef WAVE_RED

  if (lane == 0) {
    const size_t stride = (size_t)3 * N;
    float* o0 = out + 3 * (size_t)n;             // rgb
    float* o1 = o0 + stride;                     // wo_indir
    float* o2 = o1 + stride;                     // wo_vis
    float* o3 = o2 + stride;                     // indir
    o0[0] = lin2srgb(clamp01(s1r + s3r));
    o0[1] = lin2srgb(clamp01(s1g + s3g));
    o0[2] = lin2srgb(clamp01(s1b + s3b));
    o1[0] = lin2srgb(s1r); o1[1] = lin2srgb(s1g); o1[2] = lin2srgb(s1b);
    o2[0] = lin2srgb(s2r); o2[1] = lin2srgb(s2g); o2[2] = lin2srgb(s2b);
    o3[0] = lin2srgb(s3r); o3[1] = lin2srgb(s3g); o3[2] = lin2srgb(s3b);
  }
}

extern "C" void kernel_launch(void* const* d_in, const int* in_sizes, int n_in,
                              void* d_out, int out_size, void* d_ws, size_t ws_size,
                              hipStream_t stream) {
  const float* viewdirs   = (const float*)d_in[0];
  const float* albedo     = (const float*)d_in[1];
  const float* roughness  = (const float*)d_in[2];
  const float* fresnel    = (const float*)d_in[3];
  const float* normal     = (const float*)d_in[4];
  const float* light_dirs = (const float*)d_in[5];
  const float* law        = (const float*)d_in[6];
  const float* env_rgbs   = (const float*)d_in[7];
  const float* visibility = (const float*)d_in[8];
  const float* indirect   = (const float*)d_in[9];
  float* out = (float*)d_out;

  const int N = in_sizes[0] / 3;
  const int L = in_sizes[6];   // light_area_weight is (L,)

  dim3 block(256);
  dim3 grid((N + 3) / 4);  // 4 points (waves) per block

  if (L == 512) {
    hipLaunchKernelGGL(tensoir_render<512>, grid, block, 0, stream,
                       viewdirs, albedo, roughness, fresnel, normal,
                       light_dirs, law, env_rgbs, visibility, indirect,
                       out, N, L);
  } else {
    hipLaunchKernelGGL(tensoir_render<0>, grid, block, 0, stream,
                       viewdirs, albedo, roughness, fresnel, normal,
                       light_dirs, law, env_rgbs, visibility, indirect,
                       out, N, L);
  }
}